// Round 10
// baseline (755.228 us; speedup 1.0000x reference)
//
#include <hip/hip_runtime.h>

#define HID 768
#define WPB 16     // words per tile
#define ROWS 64    // subword rows per tile
#define BK 64      // K-chunk width
#define NCH 12     // 768 / 64 K-chunks

typedef __attribute__((ext_vector_type(4))) float f32x4;
typedef __attribute__((ext_vector_type(8))) short s16x8;
typedef __attribute__((ext_vector_type(4))) short s16x4;

__device__ inline short f2bf(float f) {
  unsigned u = __builtin_bit_cast(unsigned, f);
  u = (u + 0x7fffu + ((u >> 16) & 1u)) >> 16;
  return (short)(unsigned short)u;
}
__device__ inline float fast_tanh(float v) {
  float e = exp2f(v * 2.885390081777927f);   // e^{2v}
  return 1.0f - 2.0f * __builtin_amdgcn_rcpf(e + 1.0f);
}
__device__ inline s16x8 pack8(f32x4 f0, f32x4 f1) {
  s16x8 p;
  p[0]=f2bf(f0[0]); p[1]=f2bf(f0[1]); p[2]=f2bf(f0[2]); p[3]=f2bf(f0[3]);
  p[4]=f2bf(f1[0]); p[5]=f2bf(f1[1]); p[6]=f2bf(f1[2]); p[7]=f2bf(f1[3]);
  return p;
}
__device__ inline s16x4 pack4(f32x4 f) {
  s16x4 p;
  p[0]=f2bf(f[0]); p[1]=f2bf(f[1]); p[2]=f2bf(f[2]); p[3]=f2bf(f[3]);
  return p;
}

// ---- pre-pass: W fp32 -> bf16 in MFMA FRAGMENT ORDER (verified r7/r8) ----
__global__ void wconv_kernel(const float* __restrict__ W, short* __restrict__ Wb, int n64) {
  int gid = blockIdx.x * blockDim.x + threadIdx.x;
  if (gid >= n64) return;                  // n64 = 24*48*64 = 73728
  int lane = gid & 63;
  int frag = gid >> 6;
  int kc = frag / 48;                      // 0..23
  int t  = frag - kc * 48;                 // 0..47
  int col = t * 16 + (lane & 15);
  int k0  = kc * 32 + (lane >> 4) * 8;
  const float* src = W + (size_t)col * HID + k0;
  f32x4 f0 = *(const f32x4*)src;
  f32x4 f1 = *(const f32x4*)(src + 4);
  *(s16x8*)(Wb + (size_t)gid * 8) = pack8(f0, f1);
}

// MODE 0: full fused kernel (writes d_out). MODE 1: GEMM+scorer only
// (writes s to sdiag, skips pooling) - diagnostic.
template<bool USE_WB, int MODE>
__global__ __launch_bounds__(1024, 1) void fused_kernel(
    const float* __restrict__ x, const short* __restrict__ Wb,
    const float* __restrict__ Wf, const float* __restrict__ bias,
    const float* __restrict__ scw, const int* __restrict__ mapping,
    float* __restrict__ out, int num_words, float* __restrict__ sdiag)
{
  __shared__ short Abuf[2 * ROWS * BK];   // 16 KB, XOR-swizzled, double-buffered
  __shared__ float s_lds[ROWS];           // attention logits

  const int tid = threadIdx.x;
  const int tile = blockIdx.x;
  const int w0 = tile * WPB;
  const int wlast = min(w0 + WPB - 1, num_words - 1);
  const int r0 = mapping[2 * w0];
  const int r1 = mapping[2 * wlast + 1];
  const int nrows = min(r1 - r0, ROWS);

  const int srow = tid >> 4;
  const int sslot = tid & 15;
  const bool sok = srow < nrows;
  const float* xs = x + (size_t)(r0 + srow) * HID + sslot * 4;
  char* wsw = (char*)Abuf + srow * 128 + ((sslot * 8) ^ ((srow & 7) << 4));

  f32x4 pfA, pfB;

  #define ISSUE(PF, CH) do {                                       \
      PF = sok ? *(const f32x4*)(xs + (CH) * BK) : (f32x4){0,0,0,0}; } while(0)

  #define CVTW(PF, BUFI) do {                                      \
      *(s16x4*)(wsw + (BUFI) * (ROWS * BK * 2)) = pack4(PF); } while(0)

  #define BARRIER() do {                                           \
      asm volatile("s_waitcnt lgkmcnt(0)" ::: "memory");           \
      __builtin_amdgcn_s_barrier(); } while(0)

  if (tid < ROWS) s_lds[tid] = 0.0f;

  const int lane = tid & 63;
  const int wave = tid >> 6;          // 0..15, owns 48-col strip
  const int l15 = lane & 15;
  const int lk  = lane >> 4;          // 0..3
  const int c0  = wave * 48;
  const char* abase = (const char*)Abuf + l15 * 128;
  const int col0 = (lk * 16) ^ ((l15 & 7) << 4);   // kk=0 16B slot (swizzled)
  const int col1 = col0 ^ 64;                      // kk=32 slot

  const short* B2 = Wb + (size_t)(wave * 3) * 512 + lane * 8;
  const float* Bf = Wf + (size_t)(c0 + l15) * HID + lk * 8;

  auto loadB = [&](int n, int kc) -> s16x8 {   // kc = 32-wide chunk idx, 0..23
    if constexpr (USE_WB) {
      return *(const s16x8*)(B2 + (size_t)kc * 24576 + n * 512);
    } else {
      f32x4 g0 = *(const f32x4*)(Bf + n * (16 * HID) + kc * 32);
      f32x4 g1 = *(const f32x4*)(Bf + n * (16 * HID) + kc * 32 + 4);
      return pack8(g0, g1);
    }
  };

  f32x4 acc[4][3];
  #pragma unroll
  for (int m = 0; m < 4; ++m)
    #pragma unroll
    for (int n = 0; n < 3; ++n) acc[m][n] = (f32x4){0,0,0,0};

  s16x8 bE[3], bO[3];

  ISSUE(pfA, 0);
  ISSUE(pfB, 1);
  #pragma unroll
  for (int n = 0; n < 3; ++n) bE[n] = loadB(n, 0);
  CVTW(pfA, 0);
  BARRIER();

  #define CHUNK(C, PFI, ICH, PFW) do {                                       \
    const int bufi = (C) & 1;                                                \
    const char* ab = abase + bufi * (ROWS * BK * 2);                         \
    _Pragma("unroll")                                                        \
    for (int n = 0; n < 3; ++n) bO[n] = loadB(n, (C) * 2 + 1);               \
    ISSUE(PFI, (ICH) < NCH ? (ICH) : NCH - 1);                               \
    {                                                                        \
      s16x8 a0 = *(const s16x8*)(ab + 0 * (16*128) + col0);                  \
      s16x8 a1 = *(const s16x8*)(ab + 1 * (16*128) + col0);                  \
      s16x8 a2 = *(const s16x8*)(ab + 2 * (16*128) + col0);                  \
      s16x8 a3 = *(const s16x8*)(ab + 3 * (16*128) + col0);                  \
      __builtin_amdgcn_s_setprio(1);                                         \
      _Pragma("unroll")                                                      \
      for (int n = 0; n < 3; ++n) {                                          \
        acc[0][n] = __builtin_amdgcn_mfma_f32_16x16x32_bf16(a0, bE[n], acc[0][n], 0,0,0); \
        acc[1][n] = __builtin_amdgcn_mfma_f32_16x16x32_bf16(a1, bE[n], acc[1][n], 0,0,0); \
        acc[2][n] = __builtin_amdgcn_mfma_f32_16x16x32_bf16(a2, bE[n], acc[2][n], 0,0,0); \
        acc[3][n] = __builtin_amdgcn_mfma_f32_16x16x32_bf16(a3, bE[n], acc[3][n], 0,0,0); \
      }                                                                      \
      __builtin_amdgcn_s_setprio(0);                                         \
    }                                                                        \
    {                                                                        \
      const int tn = (C) * 2 + 2;                                            \
      _Pragma("unroll")                                                      \
      for (int n = 0; n < 3; ++n) bE[n] = loadB(n, tn < 24 ? tn : 23);       \
      s16x8 a0 = *(const s16x8*)(ab + 0 * (16*128) + col1);                  \
      s16x8 a1 = *(const s16x8*)(ab + 1 * (16*128) + col1);                  \
      s16x8 a2 = *(const s16x8*)(ab + 2 * (16*128) + col1);                  \
      s16x8 a3 = *(const s16x8*)(ab + 3 * (16*128) + col1);                  \
      __builtin_amdgcn_s_setprio(1);                                         \
      _Pragma("unroll")                                                      \
      for (int n = 0; n < 3; ++n) {                                          \
        acc[0][n] = __builtin_amdgcn_mfma_f32_16x16x32_bf16(a0, bO[n], acc[0][n], 0,0,0); \
        acc[1][n] = __builtin_amdgcn_mfma_f32_16x16x32_bf16(a1, bO[n], acc[1][n], 0,0,0); \
        acc[2][n] = __builtin_amdgcn_mfma_f32_16x16x32_bf16(a2, bO[n], acc[2][n], 0,0,0); \
        acc[3][n] = __builtin_amdgcn_mfma_f32_16x16x32_bf16(a3, bO[n], acc[3][n], 0,0,0); \
      }                                                                      \
      __builtin_amdgcn_s_setprio(0);                                         \
    }                                                                        \
    if ((C) + 1 < NCH) CVTW(PFW, bufi ^ 1);                                  \
    BARRIER();                                                               \
  } while(0)

  #pragma unroll 1
  for (int ch = 0; ch < NCH; ch += 2) {
    CHUNK(ch,     pfA, ch + 2, pfB);
    CHUNK(ch + 1, pfB, ch + 3, pfA);
  }

  // --- tanh + scorer dot, reduce 16 lanes -> s_lds ---
  float wv[3], bv[3];
  #pragma unroll
  for (int n = 0; n < 3; ++n) {
    int col = c0 + n * 16 + l15;
    wv[n] = scw[col];
    bv[n] = bias[col];
  }
  #pragma unroll
  for (int m = 0; m < 4; ++m) {
    #pragma unroll
    for (int r = 0; r < 4; ++r) {
      float v = 0.0f;
      #pragma unroll
      for (int n = 0; n < 3; ++n)
        v += fast_tanh(acc[m][n][r] + bv[n]) * wv[n];
      v += __shfl_xor(v, 1);
      v += __shfl_xor(v, 2);
      v += __shfl_xor(v, 4);
      v += __shfl_xor(v, 8);
      if (l15 == 0) atomicAdd(&s_lds[m * 16 + lk * 4 + r], v);
    }
  }
  __syncthreads();

  if constexpr (MODE == 1) {
    // diagnostic: stop after the GEMM+scorer phase; dump s and exit
    if (tid < ROWS) sdiag[(size_t)tile * ROWS + tid] = s_lds[tid];
    return;
  }

  // --- per-word softmax + weighted sum, x re-read fp32 (L2/L3-resident) ---
  const float LOG2E = 1.4426950408889634f;
  int gw = w0 + wave;                  // 16 waves <-> 16 words
  if (wave < WPB && gw < num_words) {
    int grs = mapping[2 * gw];
    int lrs = grs - r0;
    int cnt = min(mapping[2 * gw + 1] - r0, nrows) - lrs;
    float mmax = -3.0e38f;
    for (int i = 0; i < cnt; ++i) mmax = fmaxf(mmax, s_lds[lrs + i]);
    float denom = 0.0f;
    for (int i = 0; i < cnt; ++i) denom += exp2f((s_lds[lrs + i] - mmax) * LOG2E);
    float rden = (denom > 0.0f) ? (1.0f / denom) : 0.0f;
    float pb[8];
    #pragma unroll
    for (int i = 0; i < 8; ++i)
      pb[i] = (i < cnt) ? exp2f((s_lds[lrs + i] - mmax) * LOG2E) * rden : 0.0f;
    #pragma unroll
    for (int j = 0; j < 3; ++j) {
      int col = j * 256 + lane * 4;
      const float* xb = x + (size_t)grs * HID + col;
      f32x4 o = {0, 0, 0, 0};
      #pragma unroll
      for (int i = 0; i < 8; ++i) {
        if (i < cnt) {
          f32x4 xv = *(const f32x4*)(xb + (size_t)i * HID);
          o[0] += pb[i] * xv[0];
          o[1] += pb[i] * xv[1];
          o[2] += pb[i] * xv[2];
          o[3] += pb[i] * xv[3];
        }
      }
      for (int i = 8; i < cnt; ++i) {   // generality tail (unused for this data)
        float p = exp2f((s_lds[lrs + i] - mmax) * LOG2E) * rden;
        f32x4 xv = *(const f32x4*)(xb + (size_t)i * HID);
        o[0] += p * xv[0];
        o[1] += p * xv[1];
        o[2] += p * xv[2];
        o[3] += p * xv[3];
      }
      *(f32x4*)(out + (size_t)gw * HID + col) = o;
    }
  }
  #undef ISSUE
  #undef CVTW
  #undef BARRIER
  #undef CHUNK
}

// ---- diagnostic: the pooling epilogue alone, reading s from sdiag ----
__global__ __launch_bounds__(1024, 1) void pool_diag(
    const float* __restrict__ x, const float* __restrict__ sdiag,
    const int* __restrict__ mapping, float* __restrict__ poolws, int num_words)
{
  const int tid = threadIdx.x;
  const int tile = blockIdx.x;
  const int w0 = tile * WPB;
  const int wlast = min(w0 + WPB - 1, num_words - 1);
  const int r0 = mapping[2 * w0];
  const int r1 = mapping[2 * wlast + 1];
  const int nrows = min(r1 - r0, ROWS);
  const int lane = tid & 63;
  const int wave = tid >> 6;
  const float* sl = sdiag + (size_t)tile * ROWS;
  const float LOG2E = 1.4426950408889634f;
  int gw = w0 + wave;
  if (wave < WPB && gw < num_words) {
    int grs = mapping[2 * gw];
    int lrs = grs - r0;
    int cnt = min(mapping[2 * gw + 1] - r0, nrows) - lrs;
    float mmax = -3.0e38f;
    for (int i = 0; i < cnt; ++i) mmax = fmaxf(mmax, sl[lrs + i]);
    float denom = 0.0f;
    for (int i = 0; i < cnt; ++i) denom += exp2f((sl[lrs + i] - mmax) * LOG2E);
    float rden = (denom > 0.0f) ? (1.0f / denom) : 0.0f;
    float pb[8];
    #pragma unroll
    for (int i = 0; i < 8; ++i)
      pb[i] = (i < cnt) ? exp2f((sl[lrs + i] - mmax) * LOG2E) * rden : 0.0f;
    #pragma unroll
    for (int j = 0; j < 3; ++j) {
      int col = j * 256 + lane * 4;
      const float* xb = x + (size_t)grs * HID + col;
      f32x4 o = {0, 0, 0, 0};
      #pragma unroll
      for (int i = 0; i < 8; ++i) {
        if (i < cnt) {
          f32x4 xv = *(const f32x4*)(xb + (size_t)i * HID);
          o[0] += pb[i] * xv[0];
          o[1] += pb[i] * xv[1];
          o[2] += pb[i] * xv[2];
          o[3] += pb[i] * xv[3];
        }
      }
      for (int i = 8; i < cnt; ++i) {
        float p = exp2f((sl[lrs + i] - mmax) * LOG2E) * rden;
        f32x4 xv = *(const f32x4*)(xb + (size_t)i * HID);
        o[0] += p * xv[0];
        o[1] += p * xv[1];
        o[2] += p * xv[2];
        o[3] += p * xv[3];
      }
      // store into a small rotating ws window (diagnostic only)
      float* ob = poolws + ((size_t)((tile & 7) * WPB + wave) * HID);
      *(f32x4*)(ob + col) = o;
    }
  }
}

extern "C" void kernel_launch(void* const* d_in, const int* in_sizes, int n_in,
                              void* d_out, int out_size, void* d_ws, size_t ws_size,
                              hipStream_t stream) {
  const float* x    = (const float*)d_in[0];
  const float* W    = (const float*)d_in[1];
  const float* bias = (const float*)d_in[2];
  const float* scw  = (const float*)d_in[3];
  // d_in[4] (scorer bias) shifts every logit equally -> cancels in softmax
  const int* mapping = (const int*)d_in[5];
  float* out = (float*)d_out;

  int num_words = in_sizes[5] / 2;
  int nblocks = (num_words + WPB - 1) / WPB;

  size_t wb_bytes = (size_t)HID * HID * sizeof(short);
  char* wsb = (char*)d_ws;
  if (ws_size >= wb_bytes) {
    short* Wb = (short*)wsb;
    int n64 = (HID / 32) * (HID / 16) * 64;   // 73728 fragment-lane slots
    wconv_kernel<<<(n64 + 255) / 256, 256, 0, stream>>>(W, Wb, n64);
    fused_kernel<true, 0><<<nblocks, 1024, 0, stream>>>(
        x, Wb, W, bias, scw, mapping, out, num_words, nullptr);

    // ---- diagnostics (1/4 grid, write only into d_ws; removed next round) ----
    const int DIAG_TILES = 1024;
    if (ws_size >= (size_t)(2u << 20) && nblocks >= DIAG_TILES) {
      float* sdiag  = (float*)(wsb + 1310720);   // 1024*64*4 = 256 KB
      float* poolws = (float*)(wsb + 1572864);   // 8*16*768*4 = 384 KB
      fused_kernel<true, 1><<<DIAG_TILES, 1024, 0, stream>>>(
          x, Wb, W, bias, scw, mapping, out, num_words, sdiag);
      pool_diag<<<DIAG_TILES, 1024, 0, stream>>>(x, sdiag, mapping, poolws, num_words);
    }
  } else {
    fused_kernel<false, 0><<<nblocks, 1024, 0, stream>>>(
        x, nullptr, W, bias, scw, mapping, out, num_words, nullptr);
  }
}